// Round 3
// baseline (1185.989 us; speedup 1.0000x reference)
//
#include <hip/hip_runtime.h>
#include <math.h>

#define N     128
#define NC    40
#define BB    4096
#define XT_S  132  // transposed-chunk row stride: fast dim n=0..127, +4 pad
                   // store bank = (16fq+4k+n) mod 32 -> 2-way only (free)
#define YS_S  68   // y/h stride: float4-aligned, padded vs 64

// ---------------------------------------------------------------------------
// prep1: A_norm = D^-1/2 (A + I) D^-1/2 from tril edge weights. 1 block.
// ---------------------------------------------------------------------------
__global__ void prep_anorm(const float* __restrict__ edge_w,
                           float* __restrict__ An_out) {
    __shared__ float Ah[N][N + 1];
    __shared__ float dinv[N];
    const int t  = threadIdx.x;
    const int i  = t >> 1;
    const int jh = (t & 1) * 64;
    for (int jj = 0; jj < 64; ++jj) {
        int j  = jh + jj;
        int hi = i >= j ? i : j;
        int lo = i >= j ? j : i;
        float a = edge_w[hi * (hi + 1) / 2 + lo];
        if (i == j) a += 1.0f;
        Ah[i][j] = a;
    }
    __syncthreads();
    if (t < N) {
        float s = 0.0f;
        for (int j = 0; j < N; ++j) s += Ah[t][j];
        dinv[t] = s > 0.0f ? 1.0f / sqrtf(s) : 0.0f;
    }
    __syncthreads();
    for (int jj = 0; jj < 64; ++jj) {
        int j = jh + jj;
        An_out[i * N + j] = dinv[i] * Ah[i][j] * dinv[j];
    }
}

// ---------------------------------------------------------------------------
// prep2: A2 = An @ An. 128 blocks x 128 threads.
// ---------------------------------------------------------------------------
__global__ void prep_a2(const float* __restrict__ An, float* __restrict__ A2) {
    const int i = blockIdx.x;
    const int j = threadIdx.x;
    float acc = 0.0f;
    for (int k = 0; k < N; ++k)
        acc += An[i * N + k] * An[k * N + j];
    A2[i * N + j] = acc;
}

// ---------------------------------------------------------------------------
// main fused kernel, one batch element per block.
//   Phase 1: y = x[b] @ lin_w        Phase 2: h = A2 @ y
//   epilogue: relu(+lin_b), conv_w pool, relu, fc.
// Thread (tm=t&31, hg=t>>5): rows 4*tm..4*tm+3, cols hg*8..hg*8+7.
// LDS: uni = lin_w (stride 64, phase 1) UNION ys (stride 68, phase 2+);
//      xs  = double-buffered transposed 16-col chunks (xs_t[f][n], n fast).
// 51.7 KB LDS -> 3 blocks/CU -> 12 waves/CU.
// ---------------------------------------------------------------------------
__global__ __launch_bounds__(256, 3) void dgcnn_main(
    const float* __restrict__ x, const float* __restrict__ A2,
    const float* __restrict__ lin_w, const float* __restrict__ lin_b,
    const float* __restrict__ conv_w, const float* __restrict__ conv_b,
    const float* __restrict__ fc_w, const float* __restrict__ fc_b,
    float* __restrict__ out) {
    __shared__ __align__(16) float uni[N * YS_S];     // 34816 B
    __shared__ __align__(16) float xs[2][16 * XT_S];  // 16896 B
    float* lw = uni;   // [128][64], phase 1 only
    float* ys = uni;   // [128][68], phase 2 + epilogue

    const int t  = threadIdx.x;
    const int b  = blockIdx.x;
    const int tm = t & 31;
    const int hg = t >> 5;
    const int h0 = hg * 8;
    const int n0 = 4 * tm;

    const float* xb = x + (size_t)b * (N * N);

    // stage lin_w (2048 float4) into LDS
    {
        const float4* g = (const float4*)lin_w;
        float4* s = (float4*)lw;
#pragma unroll
        for (int r = 0; r < 8; ++r) s[t + 256 * r] = g[t + 256 * r];
    }
    // stage chunk 0 of x, transposed: xs[0][f_local][n] = x[n][f_local]
    {
        const float4* g = (const float4*)xb;
#pragma unroll
        for (int half = 0; half < 2; ++half) {
            int l4 = t + 256 * half;
            int n = l4 >> 2, fq = l4 & 3;
            float4 v = g[n * 32 + fq];
            float* d = &xs[0][0];
            d[(4 * fq + 0) * XT_S + n] = v.x;
            d[(4 * fq + 1) * XT_S + n] = v.y;
            d[(4 * fq + 2) * XT_S + n] = v.z;
            d[(4 * fq + 3) * XT_S + n] = v.w;
        }
    }

    float acc[4][8];
#pragma unroll
    for (int r = 0; r < 4; ++r)
#pragma unroll
        for (int q = 0; q < 8; ++q) acc[r][q] = 0.0f;

    __syncthreads();

    // ---------------- Phase 1: y = x @ lin_w (8 chunks, double-buffered) ----
#pragma unroll 1
    for (int c = 0; c < 8; ++c) {
        float4 pf[2];
        int pn[2], pq[2];
        {   // prefetch chunk c+1 (c==7: first A2 chunk) into registers
            const float4* g = (c == 7) ? (const float4*)A2 : (const float4*)xb;
            const int f0q = (c == 7) ? 0 : (c + 1) * 4;
#pragma unroll
            for (int half = 0; half < 2; ++half) {
                int l4 = t + 256 * half;
                pn[half] = l4 >> 2; pq[half] = l4 & 3;
                pf[half] = g[pn[half] * 32 + f0q + pq[half]];
            }
        }
        const float* xsb = &xs[c & 1][0];
        const int fb = c * 16;
#pragma unroll
        for (int f = 0; f < 16; ++f) {
            float4 av = *(const float4*)&xsb[f * XT_S + n0];
            float4 w0 = *(const float4*)&lw[(fb + f) * 64 + h0];
            float4 w1 = *(const float4*)&lw[(fb + f) * 64 + h0 + 4];
            float a[4] = {av.x, av.y, av.z, av.w};
            float w[8] = {w0.x, w0.y, w0.z, w0.w, w1.x, w1.y, w1.z, w1.w};
#pragma unroll
            for (int r = 0; r < 4; ++r)
#pragma unroll
                for (int q = 0; q < 8; ++q)
                    acc[r][q] = fmaf(a[r], w[q], acc[r][q]);
        }
        {   // store prefetched chunk into the other buffer
            float* d = &xs[(c + 1) & 1][0];
#pragma unroll
            for (int half = 0; half < 2; ++half) {
                d[(4 * pq[half] + 0) * XT_S + pn[half]] = pf[half].x;
                d[(4 * pq[half] + 1) * XT_S + pn[half]] = pf[half].y;
                d[(4 * pq[half] + 2) * XT_S + pn[half]] = pf[half].z;
                d[(4 * pq[half] + 3) * XT_S + pn[half]] = pf[half].w;
            }
        }
        __syncthreads();
    }

    // spill y into ys (overwrites lw region: all lw reads completed at sync)
#pragma unroll
    for (int r = 0; r < 4; ++r) {
        float4 a0 = make_float4(acc[r][0], acc[r][1], acc[r][2], acc[r][3]);
        float4 a1 = make_float4(acc[r][4], acc[r][5], acc[r][6], acc[r][7]);
        *(float4*)&ys[(n0 + r) * YS_S + h0] = a0;
        *(float4*)&ys[(n0 + r) * YS_S + h0 + 4] = a1;
#pragma unroll
        for (int q = 0; q < 8; ++q) acc[r][q] = 0.0f;
    }
    __syncthreads();

    // ---------------- Phase 2: h = A2 @ y (8 chunks; chunk 0 already staged) -
#pragma unroll 1
    for (int c = 0; c < 8; ++c) {
        float4 pf[2];
        int pn[2], pq[2];
        if (c < 7) {
            const float4* g = (const float4*)A2;
            const int f0q = (c + 1) * 4;
#pragma unroll
            for (int half = 0; half < 2; ++half) {
                int l4 = t + 256 * half;
                pn[half] = l4 >> 2; pq[half] = l4 & 3;
                pf[half] = g[pn[half] * 32 + f0q + pq[half]];
            }
        }
        const float* xsb = &xs[c & 1][0];
        const int jb = c * 16;
#pragma unroll
        for (int j = 0; j < 16; ++j) {
            float4 av = *(const float4*)&xsb[j * XT_S + n0];
            float4 w0 = *(const float4*)&ys[(jb + j) * YS_S + h0];
            float4 w1 = *(const float4*)&ys[(jb + j) * YS_S + h0 + 4];
            float a[4] = {av.x, av.y, av.z, av.w};
            float w[8] = {w0.x, w0.y, w0.z, w0.w, w1.x, w1.y, w1.z, w1.w};
#pragma unroll
            for (int r = 0; r < 4; ++r)
#pragma unroll
                for (int q = 0; q < 8; ++q)
                    acc[r][q] = fmaf(a[r], w[q], acc[r][q]);
        }
        if (c < 7) {
            float* d = &xs[(c + 1) & 1][0];
#pragma unroll
            for (int half = 0; half < 2; ++half) {
                d[(4 * pq[half] + 0) * XT_S + pn[half]] = pf[half].x;
                d[(4 * pq[half] + 1) * XT_S + pn[half]] = pf[half].y;
                d[(4 * pq[half] + 2) * XT_S + pn[half]] = pf[half].z;
                d[(4 * pq[half] + 3) * XT_S + pn[half]] = pf[half].w;
            }
        }
        __syncthreads();
    }

    // epilogue: h = relu(acc + lin_b); scale by conv_w[n]; overwrite ys
#pragma unroll
    for (int r = 0; r < 4; ++r) {
        int n = n0 + r;
        float cw = conv_w[n];
        float4 v0, v1;
        v0.x = fmaxf(acc[r][0] + lin_b[h0 + 0], 0.0f) * cw;
        v0.y = fmaxf(acc[r][1] + lin_b[h0 + 1], 0.0f) * cw;
        v0.z = fmaxf(acc[r][2] + lin_b[h0 + 2], 0.0f) * cw;
        v0.w = fmaxf(acc[r][3] + lin_b[h0 + 3], 0.0f) * cw;
        v1.x = fmaxf(acc[r][4] + lin_b[h0 + 4], 0.0f) * cw;
        v1.y = fmaxf(acc[r][5] + lin_b[h0 + 5], 0.0f) * cw;
        v1.z = fmaxf(acc[r][6] + lin_b[h0 + 6], 0.0f) * cw;
        v1.w = fmaxf(acc[r][7] + lin_b[h0 + 7], 0.0f) * cw;
        *(float4*)&ys[n * YS_S + h0] = v0;
        *(float4*)&ys[n * YS_S + h0 + 4] = v1;
    }
    __syncthreads();

    // pooled[h] = relu(sum_n ys[n][h] + conv_b): 4-way split reduction
    float* ps   = &xs[0][0];   // 256 floats scratch
    float* pool = &xs[1][0];   // 64 floats
    {
        int h = t & 63, qr = t >> 6;
        float s = 0.0f;
#pragma unroll
        for (int i = 0; i < 32; ++i) s += ys[(qr * 32 + i) * YS_S + h];
        ps[qr * 64 + h] = s;
    }
    __syncthreads();
    if (t < 64) {
        float s = ps[t] + ps[64 + t] + ps[128 + t] + ps[192 + t] + conv_b[0];
        pool[t] = fmaxf(s, 0.0f);
    }
    __syncthreads();
    if (t < NC) {
        float o = fc_b[t];
#pragma unroll
        for (int h = 0; h < 64; ++h) o += pool[h] * fc_w[h * NC + t];
        out[(size_t)b * NC + t] = o;
    }
}

// ---------------------------------------------------------------------------
extern "C" void kernel_launch(void* const* d_in, const int* in_sizes, int n_in,
                              void* d_out, int out_size, void* d_ws, size_t ws_size,
                              hipStream_t stream) {
    const float* x      = (const float*)d_in[0];
    const float* edge_w = (const float*)d_in[1];
    const float* lin_w  = (const float*)d_in[2];
    const float* lin_b  = (const float*)d_in[3];
    const float* conv_w = (const float*)d_in[4];
    const float* conv_b = (const float*)d_in[5];
    const float* fc_w   = (const float*)d_in[6];
    const float* fc_b   = (const float*)d_in[7];
    float* out = (float*)d_out;

    float* A2 = (float*)d_ws;
    float* An = A2 + N * N;

    prep_anorm<<<1, 256, 0, stream>>>(edge_w, An);
    prep_a2<<<N, N, 0, stream>>>(An, A2);
    dgcnn_main<<<BB, 256, 0, stream>>>(x, A2, lin_w, lin_b, conv_w, conv_b,
                                       fc_w, fc_b, out);
}

// Round 4
// 543.436 us; speedup vs baseline: 2.1824x; 2.1824x over previous
//
#include <hip/hip_runtime.h>
#include <math.h>

#define N     128
#define NC    40
#define BB    4096
#define XT_S  132  // transposed-chunk row stride: fast dim n=0..127, +4 pad
#define YS_S  68   // y/h stride: float4-aligned, padded vs 64

// ---------------------------------------------------------------------------
// prep1: A_norm = D^-1/2 (A + I) D^-1/2 from tril edge weights. 1 block.
// ---------------------------------------------------------------------------
__global__ void prep_anorm(const float* __restrict__ edge_w,
                           float* __restrict__ An_out) {
    __shared__ float Ah[N][N + 1];
    __shared__ float dinv[N];
    const int t  = threadIdx.x;
    const int i  = t >> 1;
    const int jh = (t & 1) * 64;
    for (int jj = 0; jj < 64; ++jj) {
        int j  = jh + jj;
        int hi = i >= j ? i : j;
        int lo = i >= j ? j : i;
        float a = edge_w[hi * (hi + 1) / 2 + lo];
        if (i == j) a += 1.0f;
        Ah[i][j] = a;
    }
    __syncthreads();
    if (t < N) {
        float s = 0.0f;
        for (int j = 0; j < N; ++j) s += Ah[t][j];
        dinv[t] = s > 0.0f ? 1.0f / sqrtf(s) : 0.0f;
    }
    __syncthreads();
    for (int jj = 0; jj < 64; ++jj) {
        int j = jh + jj;
        An_out[i * N + j] = dinv[i] * Ah[i][j] * dinv[j];
    }
}

// ---------------------------------------------------------------------------
// prep2: A2 = An @ An. 128 blocks x 128 threads.
// ---------------------------------------------------------------------------
__global__ void prep_a2(const float* __restrict__ An, float* __restrict__ A2) {
    const int i = blockIdx.x;
    const int j = threadIdx.x;
    float acc = 0.0f;
    for (int k = 0; k < N; ++k)
        acc += An[i * N + k] * An[k * N + j];
    A2[i * N + j] = acc;
}

// ---------------------------------------------------------------------------
// main fused kernel, one batch element per block.
//   Phase 1: y = x[b] @ lin_w        Phase 2: h = A2 @ y
//   epilogue: relu(+lin_b), conv_w pool, relu, fc.
// Thread (tm=t&31, hg=t>>5): rows 4*tm..4*tm+3, cols hg*8..hg*8+7.
// LDS: uni = lin_w (stride 64, phase 1) UNION ys (stride 68, phase 2+);
//      xs  = double-buffered transposed 16-col chunks (xs_t[f][n], n fast).
// 51.7 KB LDS -> 3 blocks/CU if VGPR<=170.
// NOTE: launch_bounds min-waves MUST stay at 2 — (256,3) caps VGPR at ~170
// and spilled acc[] to scratch (2.5 GB HBM writes/dispatch, 937us — R3).
// ---------------------------------------------------------------------------
__global__ __launch_bounds__(256, 2) void dgcnn_main(
    const float* __restrict__ x, const float* __restrict__ A2,
    const float* __restrict__ lin_w, const float* __restrict__ lin_b,
    const float* __restrict__ conv_w, const float* __restrict__ conv_b,
    const float* __restrict__ fc_w, const float* __restrict__ fc_b,
    float* __restrict__ out) {
    __shared__ __align__(16) float uni[N * YS_S];     // 34816 B
    __shared__ __align__(16) float xs[2][16 * XT_S];  // 16896 B
    float* lw = uni;   // [128][64], phase 1 only
    float* ys = uni;   // [128][68], phase 2 + epilogue

    const int t  = threadIdx.x;
    const int b  = blockIdx.x;
    const int tm = t & 31;
    const int hg = t >> 5;
    const int h0 = hg * 8;
    const int n0 = 4 * tm;

    // thread-invariant staging indices (hoisted: keep loop-carried set small)
    const int pidx  = (t >> 2) * 32 + (t & 3);          // float4 index, half 0
    const int sbase = (4 * (t & 3)) * XT_S + (t >> 2);  // LDS scatter base

    const float* xb = x + (size_t)b * (N * N);
    const float4* gx = (const float4*)xb;
    const float4* ga = (const float4*)A2;

    // stage lin_w (2048 float4) into LDS
    {
        const float4* g = (const float4*)lin_w;
        float4* s = (float4*)lw;
#pragma unroll
        for (int r = 0; r < 8; ++r) s[t + 256 * r] = g[t + 256 * r];
    }
    // stage chunk 0 of x, transposed: xs[0][f_local][n] = x[n][f_local]
    {
#pragma unroll
        for (int half = 0; half < 2; ++half) {
            float4 v = gx[pidx + half * 2048];
            float* d = &xs[0][sbase + half * 64];
            d[0 * XT_S] = v.x;
            d[1 * XT_S] = v.y;
            d[2 * XT_S] = v.z;
            d[3 * XT_S] = v.w;
        }
    }

    float acc[4][8];
#pragma unroll
    for (int r = 0; r < 4; ++r)
#pragma unroll
        for (int q = 0; q < 8; ++q) acc[r][q] = 0.0f;

    __syncthreads();

    // ---------------- Phase 1: y = x @ lin_w (8 chunks, double-buffered) ----
#pragma unroll 1
    for (int c = 0; c < 8; ++c) {
        // prefetch chunk c+1 (c==7: first A2 chunk) into registers
        float4 pf0, pf1;
        {
            const float4* g = (c == 7) ? ga : gx;
            const int c4 = (c == 7) ? 0 : (c + 1) * 4;
            pf0 = g[pidx + c4];
            pf1 = g[pidx + c4 + 2048];
        }
        const float* xsb = &xs[c & 1][0];
        const int fb = c * 16;
#pragma unroll
        for (int f = 0; f < 16; ++f) {
            float4 av = *(const float4*)&xsb[f * XT_S + n0];
            float4 w0 = *(const float4*)&lw[(fb + f) * 64 + h0];
            float4 w1 = *(const float4*)&lw[(fb + f) * 64 + h0 + 4];
            float a[4] = {av.x, av.y, av.z, av.w};
            float w[8] = {w0.x, w0.y, w0.z, w0.w, w1.x, w1.y, w1.z, w1.w};
#pragma unroll
            for (int r = 0; r < 4; ++r)
#pragma unroll
                for (int q = 0; q < 8; ++q)
                    acc[r][q] = fmaf(a[r], w[q], acc[r][q]);
        }
        {   // store prefetched chunk into the other buffer
            float* d = &xs[(c + 1) & 1][sbase];
            d[0 * XT_S] = pf0.x;  d[1 * XT_S] = pf0.y;
            d[2 * XT_S] = pf0.z;  d[3 * XT_S] = pf0.w;
            d += 64;
            d[0 * XT_S] = pf1.x;  d[1 * XT_S] = pf1.y;
            d[2 * XT_S] = pf1.z;  d[3 * XT_S] = pf1.w;
        }
        __syncthreads();
    }

    // spill y into ys (overwrites lw region: all lw reads completed at sync)
#pragma unroll
    for (int r = 0; r < 4; ++r) {
        float4 a0 = make_float4(acc[r][0], acc[r][1], acc[r][2], acc[r][3]);
        float4 a1 = make_float4(acc[r][4], acc[r][5], acc[r][6], acc[r][7]);
        *(float4*)&ys[(n0 + r) * YS_S + h0] = a0;
        *(float4*)&ys[(n0 + r) * YS_S + h0 + 4] = a1;
#pragma unroll
        for (int q = 0; q < 8; ++q) acc[r][q] = 0.0f;
    }
    __syncthreads();

    // ---------------- Phase 2: h = A2 @ y (8 chunks; chunk 0 already staged) -
#pragma unroll 1
    for (int c = 0; c < 8; ++c) {
        float4 pf0, pf1;
        if (c < 7) {
            const int c4 = (c + 1) * 4;
            pf0 = ga[pidx + c4];
            pf1 = ga[pidx + c4 + 2048];
        }
        const float* xsb = &xs[c & 1][0];
        const int jb = c * 16;
#pragma unroll
        for (int j = 0; j < 16; ++j) {
            float4 av = *(const float4*)&xsb[j * XT_S + n0];
            float4 w0 = *(const float4*)&ys[(jb + j) * YS_S + h0];
            float4 w1 = *(const float4*)&ys[(jb + j) * YS_S + h0 + 4];
            float a[4] = {av.x, av.y, av.z, av.w};
            float w[8] = {w0.x, w0.y, w0.z, w0.w, w1.x, w1.y, w1.z, w1.w};
#pragma unroll
            for (int r = 0; r < 4; ++r)
#pragma unroll
                for (int q = 0; q < 8; ++q)
                    acc[r][q] = fmaf(a[r], w[q], acc[r][q]);
        }
        if (c < 7) {
            float* d = &xs[(c + 1) & 1][sbase];
            d[0 * XT_S] = pf0.x;  d[1 * XT_S] = pf0.y;
            d[2 * XT_S] = pf0.z;  d[3 * XT_S] = pf0.w;
            d += 64;
            d[0 * XT_S] = pf1.x;  d[1 * XT_S] = pf1.y;
            d[2 * XT_S] = pf1.z;  d[3 * XT_S] = pf1.w;
        }
        __syncthreads();
    }

    // epilogue: h = relu(acc + lin_b); scale by conv_w[n]; overwrite ys
#pragma unroll
    for (int r = 0; r < 4; ++r) {
        int n = n0 + r;
        float cw = conv_w[n];
        float4 v0, v1;
        v0.x = fmaxf(acc[r][0] + lin_b[h0 + 0], 0.0f) * cw;
        v0.y = fmaxf(acc[r][1] + lin_b[h0 + 1], 0.0f) * cw;
        v0.z = fmaxf(acc[r][2] + lin_b[h0 + 2], 0.0f) * cw;
        v0.w = fmaxf(acc[r][3] + lin_b[h0 + 3], 0.0f) * cw;
        v1.x = fmaxf(acc[r][4] + lin_b[h0 + 4], 0.0f) * cw;
        v1.y = fmaxf(acc[r][5] + lin_b[h0 + 5], 0.0f) * cw;
        v1.z = fmaxf(acc[r][6] + lin_b[h0 + 6], 0.0f) * cw;
        v1.w = fmaxf(acc[r][7] + lin_b[h0 + 7], 0.0f) * cw;
        *(float4*)&ys[n * YS_S + h0] = v0;
        *(float4*)&ys[n * YS_S + h0 + 4] = v1;
    }
    __syncthreads();

    // pooled[h] = relu(sum_n ys[n][h] + conv_b): 4-way split reduction
    float* ps   = &xs[0][0];   // 256 floats scratch
    float* pool = &xs[1][0];   // 64 floats
    {
        int h = t & 63, qr = t >> 6;
        float s = 0.0f;
#pragma unroll
        for (int i = 0; i < 32; ++i) s += ys[(qr * 32 + i) * YS_S + h];
        ps[qr * 64 + h] = s;
    }
    __syncthreads();
    if (t < 64) {
        float s = ps[t] + ps[64 + t] + ps[128 + t] + ps[192 + t] + conv_b[0];
        pool[t] = fmaxf(s, 0.0f);
    }
    __syncthreads();
    if (t < NC) {
        float o = fc_b[t];
#pragma unroll
        for (int h = 0; h < 64; ++h) o += pool[h] * fc_w[h * NC + t];
        out[(size_t)b * NC + t] = o;
    }
}

// ---------------------------------------------------------------------------
extern "C" void kernel_launch(void* const* d_in, const int* in_sizes, int n_in,
                              void* d_out, int out_size, void* d_ws, size_t ws_size,
                              hipStream_t stream) {
    const float* x      = (const float*)d_in[0];
    const float* edge_w = (const float*)d_in[1];
    const float* lin_w  = (const float*)d_in[2];
    const float* lin_b  = (const float*)d_in[3];
    const float* conv_w = (const float*)d_in[4];
    const float* conv_b = (const float*)d_in[5];
    const float* fc_w   = (const float*)d_in[6];
    const float* fc_b   = (const float*)d_in[7];
    float* out = (float*)d_out;

    float* A2 = (float*)d_ws;
    float* An = A2 + N * N;

    prep_anorm<<<1, 256, 0, stream>>>(edge_w, An);
    prep_a2<<<N, N, 0, stream>>>(An, A2);
    dgcnn_main<<<BB, 256, 0, stream>>>(x, A2, lin_w, lin_b, conv_w, conv_b,
                                       fc_w, fc_b, out);
}